// Round 1
// baseline (354.075 us; speedup 1.0000x reference)
//
#include <hip/hip_runtime.h>
#include <hip/hip_bf16.h>

// Problem: deformable conv (K=3, N=9, PAD=1) + BatchNorm(eval) + ReLU
// B=32, C=103, H=W=32, Cout=32. All fp32.
//
// ws layout (floats):
//   [0, 1048576)            accum  (B,32,H,W)   -- zeroed each launch
//   [1048576, 1638400)      off    (B,18,H,W)   -- offset conv output
//   [1638400, 1668064)      wt     (927,32)     -- w transposed to (c*9+n, o)

#define CC   103
#define HH   32
#define WW   32
#define NN   9
#define B_   32
#define COUT 32

#define ACC_OFF 0
#define OFF_OFF (B_ * COUT * HH * WW)                  // 1048576
#define WT_OFF  (OFF_OFF + B_ * 18 * HH * WW)          // 1638400

// ---------------- transpose main conv weight: wt[(c*9+n)*32 + o] = w[o*927 + c*9 + n]
__global__ void k_wt(const float* __restrict__ w, float* __restrict__ wt) {
    int tid = blockIdx.x * 256 + threadIdx.x;
    if (tid < COUT * CC * NN) {
        int o = tid / (CC * NN);
        int r = tid - o * (CC * NN);   // r = c*9+n
        wt[r * COUT + o] = w[tid];
    }
}

// ---------------- offset conv: off[b][oc][h][w], thread per (b, half, h, w), oc = half*9 + r
__global__ void k_off(const float* __restrict__ x, const float* __restrict__ w_off,
                      const float* __restrict__ b_off, float* __restrict__ off) {
    int tid = blockIdx.x * 256 + threadIdx.x;            // 65536 threads
    int wq   = tid & 31;
    int hq   = (tid >> 5) & 31;
    int half = (tid >> 10) & 1;
    int b    = tid >> 11;

    float acc[NN];
#pragma unroll
    for (int r = 0; r < NN; r++) acc[r] = b_off[half * 9 + r];

    const float* xb = x + b * (CC * HH * WW);
    for (int c = 0; c < CC; c++) {
        const float* xc = xb + c * (HH * WW);
        float xv[9];
#pragma unroll
        for (int ky = 0; ky < 3; ky++) {
            int yy = hq + ky - 1;
            bool rv = (unsigned)yy < 32u;
#pragma unroll
            for (int kx = 0; kx < 3; kx++) {
                int xx = wq + kx - 1;
                bool v = rv && ((unsigned)xx < 32u);
                xv[ky * 3 + kx] = v ? xc[yy * 32 + xx] : 0.f;
            }
        }
        const float* wo = w_off + (half * 9) * (CC * NN) + c * NN;
#pragma unroll
        for (int r = 0; r < NN; r++) {
#pragma unroll
            for (int k = 0; k < 9; k++)
                acc[r] = fmaf(xv[k], wo[r * (CC * NN) + k], acc[r]);
        }
    }
    float* ob = off + (b * 18 + half * 9) * (HH * WW) + hq * 32 + wq;
#pragma unroll
    for (int r = 0; r < NN; r++) ob[r * (HH * WW)] = acc[r];
}

// ---------------- deformable sample + main conv (partial over c), atomic accumulate
__global__ void k_main(const float* __restrict__ x, const float* __restrict__ off,
                       const float* __restrict__ wt, float* __restrict__ accum) {
    int tid = blockIdx.x * 256 + threadIdx.x;            // 262144 threads
    int wq = tid & 31;
    int hq = (tid >> 5) & 31;
    int b  = (tid >> 10) & 31;
    int cs = tid >> 15;                                  // 0..7 channel split
    int c0 = cs * 13;
    int c1 = min(c0 + 13, CC);

    float acc[COUT];
#pragma unroll
    for (int o = 0; o < COUT; o++) acc[o] = 0.f;

    const float* xb = x + b * (CC * HH * WW);
    const float* ob = off + b * 18 * (HH * WW) + hq * 32 + wq;

    for (int n = 0; n < NN; n++) {
        float oy = ob[n * (HH * WW)];
        float ox = ob[(9 + n) * (HH * WW)];
        float py = (float)(hq + 1 + (n / 3) - 1) + oy;
        float px = (float)(wq + 1 + (n % 3) - 1) + ox;
        py = fminf(fmaxf(py, 0.f), 33.f);
        px = fminf(fmaxf(px, 0.f), 33.f);
        int y0 = (int)py; y0 = min(y0, 32);              // py >= 0 so trunc == floor
        int x0 = (int)px; x0 = min(x0, 32);
        float wy = py - (float)y0;
        float wx = px - (float)x0;

        // corners in unpadded coords
        int u0 = y0 - 1, v0 = x0 - 1;   // top-left
        int u1 = y0,     v1 = x0;       // bottom-right rows/cols
        bool r0 = (unsigned)u0 < 32u;
        bool r1 = (unsigned)u1 < 32u;
        bool q0 = (unsigned)v0 < 32u;
        bool q1 = (unsigned)v1 < 32u;

        float w00 = (1.f - wy) * (1.f - wx); w00 = (r0 && q0) ? w00 : 0.f;
        float w01 = (1.f - wy) * wx;         w01 = (r0 && q1) ? w01 : 0.f;
        float w10 = wy * (1.f - wx);         w10 = (r1 && q0) ? w10 : 0.f;
        float w11 = wy * wx;                 w11 = (r1 && q1) ? w11 : 0.f;

        // clamped in-bounds addresses (value irrelevant when weight == 0)
        int cu0 = min(max(u0, 0), 31), cv0 = min(max(v0, 0), 31);
        int cu1 = min(max(u1, 0), 31), cv1 = min(max(v1, 0), 31);
        int s00 = cu0 * 32 + cv0;
        int s01 = cu0 * 32 + cv1;
        int s10 = cu1 * 32 + cv0;
        int s11 = cu1 * 32 + cv1;

        for (int c = c0; c < c1; c++) {
            const float* xc = xb + c * (HH * WW);
            float v00 = xc[s00], v01 = xc[s01], v10 = xc[s10], v11 = xc[s11];
            float s = v00 * w00;
            s = fmaf(v01, w01, s);
            s = fmaf(v10, w10, s);
            s = fmaf(v11, w11, s);
            const float* wr = wt + (c * NN + n) * COUT;
#pragma unroll
            for (int o = 0; o < COUT; o++)
                acc[o] = fmaf(s, wr[o], acc[o]);
        }
    }

    float* ab = accum + b * (COUT * HH * WW) + hq * 32 + wq;
#pragma unroll
    for (int o = 0; o < COUT; o++)
        atomicAdd(ab + o * (HH * WW), acc[o]);
}

// ---------------- bias + BN(eval) + ReLU
__global__ void k_bn(const float* __restrict__ accum, const float* __restrict__ bias,
                     const float* __restrict__ gamma, const float* __restrict__ beta,
                     const float* __restrict__ mean, const float* __restrict__ var,
                     float* __restrict__ out) {
    int tid = blockIdx.x * 256 + threadIdx.x;            // 1048576 threads
    int o = (tid >> 10) & 31;
    float inv = gamma[o] * rsqrtf(var[o] + 1e-5f);
    float sh  = beta[o] - mean[o] * inv;
    float v = fmaf(accum[tid] + bias[o], inv, sh);
    out[tid] = fmaxf(v, 0.f);
}

extern "C" void kernel_launch(void* const* d_in, const int* in_sizes, int n_in,
                              void* d_out, int out_size, void* d_ws, size_t ws_size,
                              hipStream_t stream) {
    const float* x      = (const float*)d_in[0];
    const float* w_off  = (const float*)d_in[1];
    const float* b_off  = (const float*)d_in[2];
    const float* w      = (const float*)d_in[3];
    const float* bias   = (const float*)d_in[4];
    const float* gamma  = (const float*)d_in[5];
    const float* beta   = (const float*)d_in[6];
    const float* rmean  = (const float*)d_in[7];
    const float* rvar   = (const float*)d_in[8];
    float* out = (float*)d_out;

    float* ws    = (float*)d_ws;
    float* accum = ws + ACC_OFF;
    float* off   = ws + OFF_OFF;
    float* wt    = ws + WT_OFF;

    // zero the accumulator (ws is poisoned to 0xAA before every timed launch)
    hipMemsetAsync(accum, 0, (size_t)(B_ * COUT * HH * WW) * sizeof(float), stream);

    k_wt  <<<(COUT * CC * NN + 255) / 256, 256, 0, stream>>>(w, wt);
    k_off <<<(B_ * 2 * HH * WW) / 256,     256, 0, stream>>>(x, w_off, b_off, off);
    k_main<<<(B_ * 8 * HH * WW) / 256,     256, 0, stream>>>(x, off, wt, accum);
    k_bn  <<<(B_ * COUT * HH * WW) / 256,  256, 0, stream>>>(accum, bias, gamma, beta,
                                                             rmean, rvar, out);
}

// Round 2
// 219.838 us; speedup vs baseline: 1.6106x; 1.6106x over previous
//
#include <hip/hip_runtime.h>
#include <hip/hip_bf16.h>

// Deformable conv (K=3, N=9, PAD=1) + BN(eval) + ReLU.  B=32 C=103 H=W=32 Cout=32, fp32.
//
// ws layout (floats):
//   [0, 1048576)             accum (B,32,H,W)      -- zeroed each launch (memset)
//   [1048576, 1638400)       off   (B,18,H,W)      -- offset-conv partials, zeroed (same memset)
//   [1638400, 1668064)       wt    (927,32)        -- main weight transposed: wt[(c*9+n)*32+o]
//   [1668064, 1684750)       wofft (927,18)        -- offset weight transposed: wofft[(c*9+k)*18+oc]

#define CC   103
#define NN   9
#define B_   32
#define COUT 32

#define ACC_OFF   0
#define OFF_OFF   (B_ * COUT * 32 * 32)                 // 1048576
#define WT_OFF    (OFF_OFF + B_ * 18 * 32 * 32)         // 1638400
#define WOFFT_OFF (WT_OFF + COUT * CC * NN)             // 1668064

// ---------------- transpose both weight tensors
__global__ void k_wt(const float* __restrict__ w, const float* __restrict__ w_off,
                     float* __restrict__ wt, float* __restrict__ wofft) {
    int tid = blockIdx.x * 256 + threadIdx.x;
    if (tid < COUT * CC * NN) {
        int o = tid / (CC * NN);
        int r = tid - o * (CC * NN);
        wt[r * COUT + o] = w[tid];
    } else if (tid < COUT * CC * NN + 18 * CC * NN) {
        int t2 = tid - COUT * CC * NN;
        int o = t2 / (CC * NN);
        int r = t2 - o * (CC * NN);
        wofft[r * 18 + o] = w_off[t2];
    }
}

// ---------------- offset conv partials: thread per pixel, acc over 18 out-channels,
// c-chunk per block, atomic accumulate into `off` (pre-zeroed; bias folded into k_main).
__global__ void k_off(const float* __restrict__ x, const float* __restrict__ wofft,
                      float* __restrict__ off) {
    int bid = blockIdx.x;                  // (b:32, rg:4, cs:8) -> all wave-uniform
    int cs = bid & 7;
    int rg = (bid >> 3) & 3;
    int b  = bid >> 5;
    int c0 = (cs * CC) >> 3;
    int c1 = ((cs + 1) * CC) >> 3;

    int t  = threadIdx.x;
    int wq = t & 31;
    int hq = rg * 8 + (t >> 5);

    float acc[18];
#pragma unroll
    for (int r = 0; r < 18; r++) acc[r] = 0.f;

    const float* xb = x + b * (CC * 1024);
    for (int c = c0; c < c1; c++) {
        const float* xc = xb + c * 1024;
        float xv[9];
#pragma unroll
        for (int ky = 0; ky < 3; ky++) {
            int yy = hq + ky - 1;
            bool rv = (unsigned)yy < 32u;
#pragma unroll
            for (int kx = 0; kx < 3; kx++) {
                int xx = wq + kx - 1;
                xv[ky * 3 + kx] = (rv && (unsigned)xx < 32u) ? xc[yy * 32 + xx] : 0.f;
            }
        }
        const float* wrow = wofft + c * (NN * 18);   // uniform -> s_load
#pragma unroll
        for (int k = 0; k < 9; k++) {
#pragma unroll
            for (int r = 0; r < 18; r++)
                acc[r] = fmaf(xv[k], wrow[k * 18 + r], acc[r]);
        }
    }
    float* ob = off + (b * 18) * 1024 + hq * 32 + wq;
#pragma unroll
    for (int r = 0; r < 18; r++) atomicAdd(ob + r * 1024, acc[r]);
}

// ---------------- deformable sample + main conv partials, atomic accumulate
__global__ void k_main(const float* __restrict__ x, const float* __restrict__ off,
                       const float* __restrict__ b_off, const float* __restrict__ wt,
                       float* __restrict__ accum) {
    int bid = blockIdx.x;                  // (b:32, rg:4, cs:8) -> wave-uniform
    int cs = bid & 7;
    int rg = (bid >> 3) & 3;
    int b  = bid >> 5;
    int c0 = (cs * CC) >> 3;
    int c1 = ((cs + 1) * CC) >> 3;

    int t  = threadIdx.x;
    int wq = t & 31;
    int hq = rg * 8 + (t >> 5);

    float acc[COUT];
#pragma unroll
    for (int o = 0; o < COUT; o++) acc[o] = 0.f;

    const float* xb = x + b * (CC * 1024);
    const float* ob = off + b * 18 * 1024 + hq * 32 + wq;

    for (int n = 0; n < NN; n++) {
        float oy = ob[n * 1024] + b_off[n];          // b_off: uniform s_load
        float ox = ob[(9 + n) * 1024] + b_off[9 + n];
        float py = (float)(hq + (n / 3)) + oy;       // hq+1 + (n/3-1)
        float px = (float)(wq + (n % 3)) + ox;
        py = fminf(fmaxf(py, 0.f), 33.f);
        px = fminf(fmaxf(px, 0.f), 33.f);
        int y0 = min((int)py, 32);
        int x0 = min((int)px, 32);
        float wy = py - (float)y0;
        float wx = px - (float)x0;

        int u0 = y0 - 1, v0 = x0 - 1;    // unpadded coords
        int u1 = y0,     v1 = x0;
        bool r0 = (unsigned)u0 < 32u, r1 = (unsigned)u1 < 32u;
        bool q0 = (unsigned)v0 < 32u, q1 = (unsigned)v1 < 32u;

        float w00 = (r0 && q0) ? (1.f - wy) * (1.f - wx) : 0.f;
        float w01 = (r0 && q1) ? (1.f - wy) * wx         : 0.f;
        float w10 = (r1 && q0) ? wy * (1.f - wx)         : 0.f;
        float w11 = (r1 && q1) ? wy * wx                 : 0.f;

        int cu0 = min(max(u0, 0), 31), cv0 = min(max(v0, 0), 31);
        int cu1 = min(max(u1, 0), 31), cv1 = min(max(v1, 0), 31);
        int s00 = cu0 * 32 + cv0, s01 = cu0 * 32 + cv1;
        int s10 = cu1 * 32 + cv0, s11 = cu1 * 32 + cv1;

        int c = c0;
        // unroll x4: issue 16 gathers before consuming
        for (; c + 4 <= c1; c += 4) {
            float v[4][4];
#pragma unroll
            for (int j = 0; j < 4; j++) {
                const float* xc = xb + (c + j) * 1024;
                v[j][0] = xc[s00]; v[j][1] = xc[s01];
                v[j][2] = xc[s10]; v[j][3] = xc[s11];
            }
            float s[4];
#pragma unroll
            for (int j = 0; j < 4; j++) {
                float sv = v[j][0] * w00;
                sv = fmaf(v[j][1], w01, sv);
                sv = fmaf(v[j][2], w10, sv);
                sv = fmaf(v[j][3], w11, sv);
                s[j] = sv;
            }
#pragma unroll
            for (int j = 0; j < 4; j++) {
                const float* wr = wt + ((c + j) * NN + n) * COUT;  // uniform -> s_load
#pragma unroll
                for (int o = 0; o < COUT; o++)
                    acc[o] = fmaf(s[j], wr[o], acc[o]);
            }
        }
        for (; c < c1; c++) {
            const float* xc = xb + c * 1024;
            float sv = xc[s00] * w00;
            sv = fmaf(xc[s01], w01, sv);
            sv = fmaf(xc[s10], w10, sv);
            sv = fmaf(xc[s11], w11, sv);
            const float* wr = wt + (c * NN + n) * COUT;
#pragma unroll
            for (int o = 0; o < COUT; o++)
                acc[o] = fmaf(sv, wr[o], acc[o]);
        }
    }

    float* ab = accum + b * (COUT * 1024) + hq * 32 + wq;
#pragma unroll
    for (int o = 0; o < COUT; o++)
        atomicAdd(ab + o * 1024, acc[o]);
}

// ---------------- bias + BN(eval) + ReLU
__global__ void k_bn(const float* __restrict__ accum, const float* __restrict__ bias,
                     const float* __restrict__ gamma, const float* __restrict__ beta,
                     const float* __restrict__ mean, const float* __restrict__ var,
                     float* __restrict__ out) {
    int tid = blockIdx.x * 256 + threadIdx.x;
    int o = (tid >> 10) & 31;
    float inv = gamma[o] * rsqrtf(var[o] + 1e-5f);
    float sh  = beta[o] - mean[o] * inv;
    float v = fmaf(accum[tid] + bias[o], inv, sh);
    out[tid] = fmaxf(v, 0.f);
}

extern "C" void kernel_launch(void* const* d_in, const int* in_sizes, int n_in,
                              void* d_out, int out_size, void* d_ws, size_t ws_size,
                              hipStream_t stream) {
    const float* x      = (const float*)d_in[0];
    const float* w_off  = (const float*)d_in[1];
    const float* b_off  = (const float*)d_in[2];
    const float* w      = (const float*)d_in[3];
    const float* bias   = (const float*)d_in[4];
    const float* gamma  = (const float*)d_in[5];
    const float* beta   = (const float*)d_in[6];
    const float* rmean  = (const float*)d_in[7];
    const float* rvar   = (const float*)d_in[8];
    float* out = (float*)d_out;

    float* ws    = (float*)d_ws;
    float* accum = ws + ACC_OFF;
    float* off   = ws + OFF_OFF;
    float* wt    = ws + WT_OFF;
    float* wofft = ws + WOFFT_OFF;

    // zero accum + off in one shot (contiguous)
    hipMemsetAsync(accum, 0, (size_t)(OFF_OFF + B_ * 18 * 1024 - ACC_OFF) * sizeof(float),
                   stream);

    int wt_elems = COUT * CC * NN + 18 * CC * NN;
    k_wt  <<<(wt_elems + 255) / 256, 256, 0, stream>>>(w, w_off, wt, wofft);
    k_off <<<1024, 256, 0, stream>>>(x, wofft, off);
    k_main<<<1024, 256, 0, stream>>>(x, off, b_off, wt, accum);
    k_bn  <<<(B_ * COUT * 1024) / 256, 256, 0, stream>>>(accum, bias, gamma, beta,
                                                         rmean, rvar, out);
}

// Round 3
// 197.395 us; speedup vs baseline: 1.7937x; 1.1137x over previous
//
#include <hip/hip_runtime.h>
#include <hip/hip_bf16.h>

// Deformable conv (K=3, N=9, PAD=1) + BN(eval) + ReLU.  B=32 C=103 H=W=32 Cout=32, fp32.
// Round 3: LDS-staged x planes. Block = (b, c-chunk of 13), 1024 threads = 1/pixel.
// Gathers hit LDS (conflict-free: bank ≈ lane), weight rows are wave-uniform s_loads,
// 18 offsets prefetched to registers before the staging barrier.
//
// ws layout (floats):
//   [0, 1048576)             accum (B,32,H,W)   -- zeroed each launch (memset)
//   [1048576, 1638400)       off   (B,18,H,W)   -- offset-conv partials, zeroed (same memset)
//   [1638400, 1668064)       wt    (927,32)     -- main weight transposed: wt[(c*9+n)*32+o]
//   [1668064, 1684750)       wofft (927,18)     -- offset weight transposed: wofft[(c*9+k)*18+oc]

#define CC   103
#define NN   9
#define B_   32
#define COUT 32
#define CHUNK 13          // 8 chunks: 7x13 + 1x12

#define ACC_OFF   0
#define OFF_OFF   (B_ * COUT * 1024)                    // 1048576
#define WT_OFF    (OFF_OFF + B_ * 18 * 1024)            // 1638400
#define WOFFT_OFF (WT_OFF + COUT * CC * NN)             // 1668064

// ---------------- transpose both weight tensors
__global__ void k_wt(const float* __restrict__ w, const float* __restrict__ w_off,
                     float* __restrict__ wt, float* __restrict__ wofft) {
    int tid = blockIdx.x * 256 + threadIdx.x;
    if (tid < COUT * CC * NN) {
        int o = tid / (CC * NN);
        int r = tid - o * (CC * NN);
        wt[r * COUT + o] = w[tid];
    } else if (tid < COUT * CC * NN + 18 * CC * NN) {
        int t2 = tid - COUT * CC * NN;
        int o = t2 / (CC * NN);
        int r = t2 - o * (CC * NN);
        wofft[r * 18 + o] = w_off[t2];
    }
}

// ---------------- offset conv partials (3x3, pad 1) with LDS-staged planes
__global__ void __launch_bounds__(1024)
k_off(const float* __restrict__ x, const float* __restrict__ wofft,
      float* __restrict__ off) {
    __shared__ float lds[CHUNK * 1024];
    int bid = blockIdx.x;              // (b:32, cs:8)
    int cs = bid & 7;
    int b  = bid >> 3;
    int c0 = cs * CHUNK;
    int nch = min(CHUNK, CC - c0);

    int t  = threadIdx.x;
    int wq = t & 31;
    int hq = t >> 5;

    const float* xb = x + b * (CC * 1024) + c0 * 1024;
    for (int i = 0; i < nch; i++)
        lds[i * 1024 + t] = xb[i * 1024 + t];
    __syncthreads();

    float acc[18];
#pragma unroll
    for (int r = 0; r < 18; r++) acc[r] = 0.f;

    for (int i = 0; i < nch; i++) {
        const float* xc = lds + i * 1024;
        float xv[9];
#pragma unroll
        for (int ky = 0; ky < 3; ky++) {
            int yy = hq + ky - 1;
            bool rv = (unsigned)yy < 32u;
#pragma unroll
            for (int kx = 0; kx < 3; kx++) {
                int xx = wq + kx - 1;
                xv[ky * 3 + kx] = (rv && (unsigned)xx < 32u) ? xc[yy * 32 + xx] : 0.f;
            }
        }
        const float* wrow = wofft + (c0 + i) * (NN * 18);   // uniform -> s_load
#pragma unroll
        for (int k = 0; k < 9; k++) {
#pragma unroll
            for (int r = 0; r < 18; r++)
                acc[r] = fmaf(xv[k], wrow[k * 18 + r], acc[r]);
        }
    }
    float* ob = off + (b * 18) * 1024 + t;
#pragma unroll
    for (int r = 0; r < 18; r++) atomicAdd(ob + r * 1024, acc[r]);
}

// ---------------- deformable sample + main conv partials with LDS-staged planes
__global__ void __launch_bounds__(1024)
k_main(const float* __restrict__ x, const float* __restrict__ off,
       const float* __restrict__ b_off, const float* __restrict__ wt,
       float* __restrict__ accum) {
    __shared__ float lds[CHUNK * 1024];
    int bid = blockIdx.x;              // (b:32, cs:8)
    int cs = bid & 7;
    int b  = bid >> 3;
    int c0 = cs * CHUNK;
    int nch = min(CHUNK, CC - c0);

    int t  = threadIdx.x;
    int wq = t & 31;
    int hq = t >> 5;

    // prefetch all 18 offsets for this pixel (overlaps with staging loads)
    const float* ob = off + b * 18 * 1024 + t;
    float offv[18];
#pragma unroll
    for (int n = 0; n < 18; n++) offv[n] = ob[n * 1024] + b_off[n];

    const float* xb = x + b * (CC * 1024) + c0 * 1024;
    for (int i = 0; i < nch; i++)
        lds[i * 1024 + t] = xb[i * 1024 + t];
    __syncthreads();

    float acc[COUT];
#pragma unroll
    for (int o = 0; o < COUT; o++) acc[o] = 0.f;

#pragma unroll
    for (int n = 0; n < NN; n++) {
        float py = (float)(hq + (n / 3)) + offv[n];       // hq+1 + (n/3-1)
        float px = (float)(wq + (n % 3)) + offv[9 + n];
        py = fminf(fmaxf(py, 0.f), 33.f);
        px = fminf(fmaxf(px, 0.f), 33.f);
        int y0 = min((int)py, 32);
        int x0 = min((int)px, 32);
        float wy = py - (float)y0;
        float wx = px - (float)x0;

        int u0 = y0 - 1, v0 = x0 - 1;    // unpadded coords
        int u1 = y0,     v1 = x0;
        bool r0 = (unsigned)u0 < 32u, r1 = (unsigned)u1 < 32u;
        bool q0 = (unsigned)v0 < 32u, q1 = (unsigned)v1 < 32u;

        float w00 = (r0 && q0) ? (1.f - wy) * (1.f - wx) : 0.f;
        float w01 = (r0 && q1) ? (1.f - wy) * wx         : 0.f;
        float w10 = (r1 && q0) ? wy * (1.f - wx)         : 0.f;
        float w11 = (r1 && q1) ? wy * wx                 : 0.f;

        int cu0 = min(max(u0, 0), 31), cv0 = min(max(v0, 0), 31);
        int cu1 = min(max(u1, 0), 31), cv1 = min(max(v1, 0), 31);
        int s00 = cu0 * 32 + cv0, s01 = cu0 * 32 + cv1;
        int s10 = cu1 * 32 + cv0, s11 = cu1 * 32 + cv1;

        const float* wr0 = wt + (c0 * NN + n) * COUT;     // uniform -> s_load
        for (int i = 0; i < nch; i++) {
            const float* xc = lds + i * 1024;
            float sv = xc[s00] * w00;
            sv = fmaf(xc[s01], w01, sv);
            sv = fmaf(xc[s10], w10, sv);
            sv = fmaf(xc[s11], w11, sv);
            const float* wr = wr0 + i * (NN * COUT);
#pragma unroll
            for (int o = 0; o < COUT; o++)
                acc[o] = fmaf(sv, wr[o], acc[o]);
        }
    }

    float* ab = accum + b * (COUT * 1024) + t;
#pragma unroll
    for (int o = 0; o < COUT; o++)
        atomicAdd(ab + o * 1024, acc[o]);
}

// ---------------- bias + BN(eval) + ReLU
__global__ void k_bn(const float* __restrict__ accum, const float* __restrict__ bias,
                     const float* __restrict__ gamma, const float* __restrict__ beta,
                     const float* __restrict__ mean, const float* __restrict__ var,
                     float* __restrict__ out) {
    int tid = blockIdx.x * 256 + threadIdx.x;
    int o = (tid >> 10) & 31;
    float inv = gamma[o] * rsqrtf(var[o] + 1e-5f);
    float sh  = beta[o] - mean[o] * inv;
    float v = fmaf(accum[tid] + bias[o], inv, sh);
    out[tid] = fmaxf(v, 0.f);
}

extern "C" void kernel_launch(void* const* d_in, const int* in_sizes, int n_in,
                              void* d_out, int out_size, void* d_ws, size_t ws_size,
                              hipStream_t stream) {
    const float* x      = (const float*)d_in[0];
    const float* w_off  = (const float*)d_in[1];
    const float* b_off  = (const float*)d_in[2];
    const float* w      = (const float*)d_in[3];
    const float* bias   = (const float*)d_in[4];
    const float* gamma  = (const float*)d_in[5];
    const float* beta   = (const float*)d_in[6];
    const float* rmean  = (const float*)d_in[7];
    const float* rvar   = (const float*)d_in[8];
    float* out = (float*)d_out;

    float* ws    = (float*)d_ws;
    float* accum = ws + ACC_OFF;
    float* off   = ws + OFF_OFF;
    float* wt    = ws + WT_OFF;
    float* wofft = ws + WOFFT_OFF;

    // zero accum + off in one shot (contiguous)
    hipMemsetAsync(accum, 0, (size_t)(WT_OFF) * sizeof(float), stream);

    int wt_elems = COUT * CC * NN + 18 * CC * NN;
    k_wt  <<<(wt_elems + 255) / 256, 256, 0, stream>>>(w, w_off, wt, wofft);
    k_off <<<256, 1024, 0, stream>>>(x, wofft, off);
    k_main<<<256, 1024, 0, stream>>>(x, off, b_off, wt, accum);
    k_bn  <<<(B_ * COUT * 1024) / 256, 256, 0, stream>>>(accum, bias, gamma, beta,
                                                         rmean, rvar, out);
}

// Round 4
// 158.845 us; speedup vs baseline: 2.2291x; 1.2427x over previous
//
#include <hip/hip_runtime.h>

// Deformable conv (K=3,N=9,PAD=1) + BN(eval) + ReLU.  B=32 C=103 H=W=32 Cout=32.
// Round 4: MFMA formulation. out[b] = W(32x927) x S[b](927x1024), S built in-register
// from zero-padded 34x34 LDS planes (no clamps, ds_read2 pairs). Full K per block ->
// no atomics, BN+ReLU fused in epilogue. bf16 operands, fp32 accumulate.

#define CC   103
#define B_   32
#define COUT 32
#define CHN  16            // channels staged per chunk
#define NCHUNK 7           // 7*16 = 112 >= 103 (pad planes/weights zero)
#define KSC  5             // k-steps (of 32) per chunk: 160 k-locals, 144 real
#define PLS  1157          // plane stride in floats (34*34=1156, +1 bank spread)
#define LDSFL (CHN * PLS)  // 18512 floats = 74048 B -> 2 blocks/CU

typedef __attribute__((ext_vector_type(8))) short bf16x8;
typedef __attribute__((ext_vector_type(4))) float f32x4;

// ws layout (floats):
#define OFF_W  0                         // off (B,18,1024) fp32
#define WTPM_W (B_ * 18 * 1024)          // 589824: main-weight frags, 35840 ushort
#define WTPO_W (WTPM_W + 17920)          // offset-weight frags, 35840 ushort
#define BN_W   (WTPO_W + 17920)          // SC[32], SH[32]

__device__ __forceinline__ unsigned short f2bf_rne(float f) {
    unsigned u = __float_as_uint(f);
    unsigned r = u + 0x7fffu + ((u >> 16) & 1u);
    return (unsigned short)(r >> 16);
}

// pack bf16(s0) into low16, bf16(s1) into high16 (round half up)
__device__ __forceinline__ unsigned pack2(float s0, float s1) {
    unsigned u0 = __float_as_uint(s0) + 0x8000u;
    unsigned u1 = __float_as_uint(s1) + 0x8000u;
    return (u1 & 0xffff0000u) | (u0 >> 16);
}

// ---------- prep: weight fragments (A-operand layout) + BN constants ----------
// A-frag for mfma_f32_16x16x32_bf16: lane l holds A[m=l&15][k=(l>>4)*8+j], j=0..7.
// k-local within chunk: kl = s*32 + (l>>4)*8 + j ; n = kl>>4 ; c = ch*16 + (kl&15).
__global__ void k_prep(const float* __restrict__ w, const float* __restrict__ w_off,
                       const float* __restrict__ bias, const float* __restrict__ gamma,
                       const float* __restrict__ beta, const float* __restrict__ mean,
                       const float* __restrict__ var,
                       unsigned short* __restrict__ wtpm,
                       unsigned short* __restrict__ wtpo,
                       float* __restrict__ bn) {
    int tid = blockIdx.x * 256 + threadIdx.x;
    if (tid < 8960) {
        bool is_main = tid < 4480;
        const float* src = is_main ? w : w_off;
        unsigned short* dst = is_main ? wtpm : wtpo;
        int mrows = is_main ? 32 : 18;
        int t = is_main ? tid : tid - 4480;
        int lane = t & 63;
        int tile = t >> 6;              // tile = (ch*5+s)*2 + mt,  70 tiles
        int mt = tile & 1;
        int chs = tile >> 1;
        int s = chs % 5, ch = chs / 5;
        int o  = mt * 16 + (lane & 15);
        int kg = lane >> 4;
        for (int j = 0; j < 8; j++) {
            int kl = s * 32 + kg * 8 + j;
            int n  = kl >> 4;
            int c  = ch * 16 + (kl & 15);
            float v = 0.f;
            if (n < 9 && c < CC && o < mrows)
                v = src[o * (CC * 9) + c * 9 + n];
            dst[(tile * 64 + lane) * 8 + j] = f2bf_rne(v);
        }
    } else if (tid < 8992) {
        int o = tid - 8960;
        float inv = gamma[o] * rsqrtf(var[o] + 1e-5f);
        bn[o]      = inv;
        bn[32 + o] = beta[o] + (bias[o] - mean[o]) * inv;
    }
}

// ---------- stage one 16-channel chunk as zero-padded 34x34 planes ----------
// Borders pre-zeroed once; interior rewritten per chunk. c>=103 -> zeros.
__device__ __forceinline__ void stage_chunk(const float* __restrict__ xb, int ch,
                                            float* __restrict__ lds, int t) {
    int rlane = t >> 3;                // row 0..31 within plane
    int c4    = (t & 7) * 4;           // col group
#pragma unroll
    for (int p = 0; p < CHN; p++) {    // plane == pass
        int c = ch * CHN + p;
        float4 v = make_float4(0.f, 0.f, 0.f, 0.f);
        if (c < CC) v = *(const float4*)(xb + c * 1024 + rlane * 32 + c4);
        float* d = lds + p * PLS + (rlane + 1) * 34 + 1 + c4;
        d[0] = v.x; d[1] = v.y; d[2] = v.z; d[3] = v.w;
    }
}

// ---------- offset conv: off(18x1024 per b) = Woff x Im2col, MFMA ----------
__global__ void __launch_bounds__(256, 2)
k_off(const float* __restrict__ x, const unsigned short* __restrict__ wtpo,
      float* __restrict__ off) {
    __shared__ float lds[LDSFL];
    int bid = blockIdx.x;              // (b:32, pxg:16)
    int pxg = bid & 15;
    int b   = bid >> 4;
    int t    = threadIdx.x;
    int lane = t & 63;
    int wv   = t >> 6;
    int px = pxg * 64 + wv * 16 + (lane & 15);
    int h = px >> 5, wq = px & 31;
    int hi  = (lane >> 5) & 1;
    int c0l = ((lane >> 4) & 1) * 8;

    for (int i = t; i < LDSFL; i += 256) lds[i] = 0.f;

    const float* xb = x + b * (CC * 1024);
    f32x4 acc0 = {0.f, 0.f, 0.f, 0.f};
    f32x4 acc1 = {0.f, 0.f, 0.f, 0.f};

    for (int ch = 0; ch < NCHUNK; ch++) {
        __syncthreads();
        stage_chunk(xb, ch, lds, t);
        __syncthreads();
        const unsigned short* wch = wtpo + (size_t)(ch * KSC) * 2 * 64 * 8;
#pragma unroll
        for (int s = 0; s < KSC; s++) {
            const int nl = 2 * s, nh = (2 * s + 1 > 8) ? 8 : 2 * s + 1;
            int ky = hi ? (nh / 3) : (nl / 3);
            int kx = hi ? (nh % 3) : (nl % 3);
            const float* cell = lds + c0l * PLS + (h + ky) * 34 + (wq + kx);
            unsigned pk[4];
#pragma unroll
            for (int jj = 0; jj < 4; jj++) {
                float s0 = cell[(2 * jj) * PLS];
                float s1 = cell[(2 * jj + 1) * PLS];
                pk[jj] = pack2(s0, s1);
            }
            union { unsigned u[4]; bf16x8 v; } bu;
            bu.u[0] = pk[0]; bu.u[1] = pk[1]; bu.u[2] = pk[2]; bu.u[3] = pk[3];
            const bf16x8* ap = (const bf16x8*)(wch + (size_t)(s * 2) * 64 * 8 + lane * 8);
            bf16x8 a0 = ap[0];
            bf16x8 a1 = ap[64];        // +64*8 shorts = next tile
            acc0 = __builtin_amdgcn_mfma_f32_16x16x32_bf16(a0, bu.v, acc0, 0, 0, 0);
            acc1 = __builtin_amdgcn_mfma_f32_16x16x32_bf16(a1, bu.v, acc1, 0, 0, 0);
        }
    }

    // D: row(M=o) = (lane>>4)*4 + reg, col(N=px) = lane&15
    int quad = lane >> 4;
    float* op = off + (size_t)b * 18 * 1024 + px;
#pragma unroll
    for (int reg = 0; reg < 4; reg++) {
        int o = quad * 4 + reg;
        op[o * 1024] = acc0[reg];
        int o2 = 16 + o;
        if (o2 < 18) op[o2 * 1024] = acc1[reg];
    }
}

// ---------- deformable sample + main conv + BN + ReLU, MFMA ----------
__global__ void __launch_bounds__(256, 2)
k_main(const float* __restrict__ x, const float* __restrict__ off,
       const float* __restrict__ b_off, const unsigned short* __restrict__ wtpm,
       const float* __restrict__ bn, float* __restrict__ out) {
    __shared__ float lds[LDSFL];
    int bid = blockIdx.x;              // (b:32, pxg:16)
    int pxg = bid & 15;
    int b   = bid >> 4;
    int t    = threadIdx.x;
    int lane = t & 63;
    int wv   = t >> 6;
    int px = pxg * 64 + wv * 16 + (lane & 15);
    int h = px >> 5, wq = px & 31;
    int hi  = (lane >> 5) & 1;
    int c0l = ((lane >> 4) & 1) * 8;
    float hf = (float)h, wf = (float)wq;

    // prefetch 18 offsets for this pixel (latency overlaps LDS zero + first stage)
    float offv[18];
    const float* ob = off + (size_t)b * 18 * 1024 + px;
#pragma unroll
    for (int n = 0; n < 18; n++) offv[n] = ob[n * 1024] + b_off[n];

    for (int i = t; i < LDSFL; i += 256) lds[i] = 0.f;

    const float* xb = x + b * (CC * 1024);
    f32x4 acc0 = {0.f, 0.f, 0.f, 0.f};
    f32x4 acc1 = {0.f, 0.f, 0.f, 0.f};

    for (int ch = 0; ch < NCHUNK; ch++) {
        __syncthreads();
        stage_chunk(xb, ch, lds, t);
        __syncthreads();
        const unsigned short* wch = wtpm + (size_t)(ch * KSC) * 2 * 64 * 8;
#pragma unroll
        for (int s = 0; s < KSC; s++) {
            const int nl = 2 * s, nh = (2 * s + 1 > 8) ? 8 : 2 * s + 1;
            float offy = hi ? offv[nh] : offv[nl];
            float offx = hi ? offv[9 + nh] : offv[9 + nl];
            float kny = (float)(hi ? (nh / 3) : (nl / 3));
            float knx = (float)(hi ? (nh % 3) : (nl % 3));
            // padded coords: p0 + kn + off = (h+1) + (n/3 - 1) + off
            float py  = fminf(fmaxf(hf + kny + offy, 0.f), 33.f);
            float pxx = fminf(fmaxf(wf + knx + offx, 0.f), 33.f);
            int y0 = min((int)py, 32);
            int x0 = min((int)pxx, 32);
            float fy = py - (float)y0;
            float fx = pxx - (float)x0;
            float w00 = (1.f - fy) * (1.f - fx), w01 = (1.f - fy) * fx;
            float w10 = fy * (1.f - fx),         w11 = fy * fx;
            const float* cell = lds + c0l * PLS + y0 * 34 + x0;
            unsigned pk[4];
#pragma unroll
            for (int jj = 0; jj < 4; jj++) {
                const float* p0 = cell + (2 * jj) * PLS;
                const float* p1 = cell + (2 * jj + 1) * PLS;
                float s0 = p0[0] * w00 + p0[1] * w01 + p0[34] * w10 + p0[35] * w11;
                float s1 = p1[0] * w00 + p1[1] * w01 + p1[34] * w10 + p1[35] * w11;
                pk[jj] = pack2(s0, s1);
            }
            union { unsigned u[4]; bf16x8 v; } bu;
            bu.u[0] = pk[0]; bu.u[1] = pk[1]; bu.u[2] = pk[2]; bu.u[3] = pk[3];
            const bf16x8* ap = (const bf16x8*)(wch + (size_t)(s * 2) * 64 * 8 + lane * 8);
            bf16x8 a0 = ap[0];
            bf16x8 a1 = ap[64];
            acc0 = __builtin_amdgcn_mfma_f32_16x16x32_bf16(a0, bu.v, acc0, 0, 0, 0);
            acc1 = __builtin_amdgcn_mfma_f32_16x16x32_bf16(a1, bu.v, acc1, 0, 0, 0);
        }
    }

    // epilogue: BN + ReLU, coalesced stores (col = px)
    int quad = lane >> 4;
    const float* SC = bn;
    const float* SH = bn + 32;
    float* op = out + (size_t)b * COUT * 1024 + px;
#pragma unroll
    for (int mt = 0; mt < 2; mt++) {
        f32x4 a = mt ? acc1 : acc0;
#pragma unroll
        for (int reg = 0; reg < 4; reg++) {
            int o = mt * 16 + quad * 4 + reg;
            float v = a[reg] * SC[o] + SH[o];
            op[o * 1024] = fmaxf(v, 0.f);
        }
    }
}

extern "C" void kernel_launch(void* const* d_in, const int* in_sizes, int n_in,
                              void* d_out, int out_size, void* d_ws, size_t ws_size,
                              hipStream_t stream) {
    const float* x      = (const float*)d_in[0];
    const float* w_off  = (const float*)d_in[1];
    const float* b_off  = (const float*)d_in[2];
    const float* w      = (const float*)d_in[3];
    const float* bias   = (const float*)d_in[4];
    const float* gamma  = (const float*)d_in[5];
    const float* beta   = (const float*)d_in[6];
    const float* rmean  = (const float*)d_in[7];
    const float* rvar   = (const float*)d_in[8];
    float* out = (float*)d_out;

    float* ws = (float*)d_ws;
    float*          offb = ws + OFF_W;
    unsigned short* wtpm = (unsigned short*)(ws + WTPM_W);
    unsigned short* wtpo = (unsigned short*)(ws + WTPO_W);
    float*          bn   = ws + BN_W;

    k_prep<<<36, 256, 0, stream>>>(w, w_off, bias, gamma, beta, rmean, rvar,
                                   wtpm, wtpo, bn);
    k_off <<<512, 256, 0, stream>>>(x, wtpo, offb);
    k_main<<<512, 256, 0, stream>>>(x, offb, b_off, wtpm, bn, out);
}

// Round 5
// 137.965 us; speedup vs baseline: 2.5664x; 1.1513x over previous
//
#include <hip/hip_runtime.h>

// Deformable conv (K=3,N=9,PAD=1) + BN(eval) + ReLU.  B=32 C=103 H=W=32 Cout=32.
// Round 5: fused offset-conv + deformable-conv in one kernel (two MFMA phases over
// the same LDS-staged zero-padded planes). Row stride 35 (odd -> 2-way max bank
// aliasing). Geometry hoisted out of the chunk loop. XCD-swizzled block decode.

#define CC   103
#define B_   32
#define COUT 32
#define CHN  16                 // channels staged per chunk
#define NCHUNK 7                // 7*16 = 112 >= 103
#define KSC  5                  // k-steps (K=32) per chunk
#define RS   35                 // plane row stride (odd -> bank spread)
#define PLS  (34 * RS)          // 1190 floats per plane
#define PLANES_FL (CHN * PLS)   // 19040 floats
#define EXCH_FL   (18 * 64)     // off-exchange: 18 channels x 64 px
#define LDS_FL    (PLANES_FL + EXCH_FL)   // 20192 floats = 80768 B

typedef __attribute__((ext_vector_type(8))) short bf16x8;
typedef __attribute__((ext_vector_type(4))) float f32x4;

// ws layout (floats):
#define WTPM_W 0                // main-weight frags: 35840 ushort = 17920 float slots
#define WTPO_W 17920            // offset-weight frags: 35840 ushort
#define BN_W   35840            // SC[32], SH[32]

__device__ __forceinline__ unsigned short f2bf_rne(float f) {
    unsigned u = __float_as_uint(f);
    unsigned r = u + 0x7fffu + ((u >> 16) & 1u);
    return (unsigned short)(r >> 16);
}
__device__ __forceinline__ unsigned pack2(float s0, float s1) {
    unsigned u0 = __float_as_uint(s0) + 0x8000u;
    unsigned u1 = __float_as_uint(s1) + 0x8000u;
    return (u1 & 0xffff0000u) | (u0 >> 16);
}

// ---------- prep: weight fragments (A-operand layout) + BN constants ----------
// A-frag 16x16x32: lane l holds A[m=l&15][k=(l>>4)*8+j].  kl = s*32+(l>>4)*8+j;
// n = kl>>4 (taps 2s, 2s+1); c = ch*16 + (kl&15).  n>=9 / c>=103 -> zero.
__global__ void k_prep(const float* __restrict__ w, const float* __restrict__ w_off,
                       const float* __restrict__ bias, const float* __restrict__ gamma,
                       const float* __restrict__ beta, const float* __restrict__ mean,
                       const float* __restrict__ var,
                       unsigned short* __restrict__ wtpm,
                       unsigned short* __restrict__ wtpo,
                       float* __restrict__ bn) {
    int tid = blockIdx.x * 256 + threadIdx.x;
    if (tid < 8960) {
        bool is_main = tid < 4480;
        const float* src = is_main ? w : w_off;
        unsigned short* dst = is_main ? wtpm : wtpo;
        int mrows = is_main ? 32 : 18;
        int t = is_main ? tid : tid - 4480;
        int lane = t & 63;
        int tile = t >> 6;              // (ch*5+s)*2 + mt, 70 tiles
        int mt = tile & 1;
        int chs = tile >> 1;
        int s = chs % 5, ch = chs / 5;
        int o  = mt * 16 + (lane & 15);
        int kg = lane >> 4;
        for (int j = 0; j < 8; j++) {
            int kl = s * 32 + kg * 8 + j;
            int n  = kl >> 4;
            int c  = ch * 16 + (kl & 15);
            float v = 0.f;
            if (n < 9 && c < CC && o < mrows)
                v = src[o * (CC * 9) + c * 9 + n];
            dst[(tile * 64 + lane) * 8 + j] = f2bf_rne(v);
        }
    } else if (tid < 8992) {
        int o = tid - 8960;
        float inv = gamma[o] * rsqrtf(var[o] + 1e-5f);
        bn[o]      = inv;
        bn[32 + o] = beta[o] + (bias[o] - mean[o]) * inv;
    }
}

// ---------- stage one 16-channel chunk into zero-padded 34x(RS) planes ----------
__device__ __forceinline__ void stage_chunk(const float* __restrict__ xb, int ch,
                                            float* __restrict__ lds, int t) {
    int r  = t >> 3;               // row 0..31
    int c4 = (t & 7) * 4;          // col group
    const float* src = xb + r * 32 + c4;
    float* dst = lds + (r + 1) * RS + 1 + c4;
#pragma unroll
    for (int p = 0; p < CHN; p++) {
        int c = ch * CHN + p;      // uniform per iteration -> scalar branch
        float4 v = make_float4(0.f, 0.f, 0.f, 0.f);
        if (c < CC) v = *(const float4*)(src + c * 1024);
        float* d = dst + p * PLS;
        d[0] = v.x; d[1] = v.y; d[2] = v.z; d[3] = v.w;
    }
}

// ---------- fused: offset conv (MFMA) -> geometry -> deformable conv (MFMA) ----------
__global__ void __launch_bounds__(256, 2)
k_fused(const float* __restrict__ x, const float* __restrict__ b_off,
        const unsigned short* __restrict__ wtpo, const unsigned short* __restrict__ wtpm,
        const float* __restrict__ bn, float* __restrict__ out) {
    __shared__ float lds[LDS_FL];
    int bid = blockIdx.x;
    // XCD swizzle: blocks sharing a batch land on one XCD (bid%8 heuristic)
    int b   = (bid & 7) * 4 + ((bid >> 3) & 3);
    int pxg = bid >> 5;

    int t = threadIdx.x, lane = t & 63, wv = t >> 6;
    int pxl = wv * 16 + (lane & 15);       // pixel-local 0..63
    int px  = pxg * 64 + pxl;
    int h = px >> 5, wq = px & 31;
    int hi = (lane >> 5) & 1;
    int quad = lane >> 4;
    int c0l = (quad & 1) * 8;

    // zero the plane region once (borders stay zero; interior rewritten per chunk)
    for (int i = t; i < PLANES_FL; i += 256) lds[i] = 0.f;

    const float* xb = x + b * (CC * 1024);
    const int TAPL[5] = {0, 2, 4, 6, 8};
    const int TAPH[5] = {1, 3, 5, 7, 8};   // s=4: tap 8 duplicated (n=9 weights are 0)

    // ================= phase 1: offset conv =================
    f32x4 acc0 = {0.f, 0.f, 0.f, 0.f};
    f32x4 acc1 = {0.f, 0.f, 0.f, 0.f};
    for (int ch = 0; ch < NCHUNK; ch++) {
        __syncthreads();
        stage_chunk(xb, ch, lds, t);
        __syncthreads();
        const unsigned short* wch = wtpo + (size_t)(ch * KSC) * 2 * 64 * 8;
#pragma unroll
        for (int s = 0; s < KSC; s++) {
            int tap = hi ? TAPH[s] : TAPL[s];
            int ky = tap / 3, kx = tap % 3;         // folds to cndmask of constants
            const float* cell = lds + c0l * PLS + (h + ky) * RS + (wq + kx);
            unsigned pk[4];
#pragma unroll
            for (int jj = 0; jj < 4; jj++)
                pk[jj] = pack2(cell[(2 * jj) * PLS], cell[(2 * jj + 1) * PLS]);
            union { unsigned u[4]; bf16x8 v; } bu;
            bu.u[0] = pk[0]; bu.u[1] = pk[1]; bu.u[2] = pk[2]; bu.u[3] = pk[3];
            const bf16x8* ap = (const bf16x8*)(wch + (size_t)(s * 2) * 64 * 8 + lane * 8);
            acc0 = __builtin_amdgcn_mfma_f32_16x16x32_bf16(ap[0],  bu.v, acc0, 0, 0, 0);
            acc1 = __builtin_amdgcn_mfma_f32_16x16x32_bf16(ap[64], bu.v, acc1, 0, 0, 0);
        }
    }

    // exchange off results through LDS (C-layout: row o = quad*4+reg, col = pxl)
    float* exch = lds + PLANES_FL;
    {
        float* ex = exch + pxl;
#pragma unroll
        for (int reg = 0; reg < 4; reg++) ex[(quad * 4 + reg) * 64] = acc0[reg];
        if (quad == 0) { ex[16 * 64] = acc1[0]; ex[17 * 64] = acc1[1]; }
    }
    __syncthreads();

    // geometry: one tap per lane per s-slot, hoisted out of the chunk loop
    int   cofs[KSC];
    float wg[KSC][4];
#pragma unroll
    for (int s = 0; s < KSC; s++) {
        int tap = hi ? TAPH[s] : TAPL[s];
        float oy = exch[tap * 64 + pxl] + b_off[tap];
        float ox = exch[(9 + tap) * 64 + pxl] + b_off[9 + tap];
        float py  = (float)(h + tap / 3) + oy;     // padded coords
        float pxx = (float)(wq + tap % 3) + ox;
        py  = fminf(fmaxf(py, 0.f), 33.f);
        pxx = fminf(fmaxf(pxx, 0.f), 33.f);
        int y0 = min((int)py, 32);
        int x0 = min((int)pxx, 32);
        float fy = py - (float)y0;
        float fx = pxx - (float)x0;
        wg[s][0] = (1.f - fy) * (1.f - fx);
        wg[s][1] = (1.f - fy) * fx;
        wg[s][2] = fy * (1.f - fx);
        wg[s][3] = fy * fx;
        cofs[s] = c0l * PLS + y0 * RS + x0;
    }

    // ================= phase 2: deformable conv =================
    acc0 = (f32x4){0.f, 0.f, 0.f, 0.f};
    acc1 = (f32x4){0.f, 0.f, 0.f, 0.f};
    for (int ch = NCHUNK - 1; ch >= 0; ch--) {     // chunk 6 still resident -> skip stage
        if (ch != NCHUNK - 1) {
            __syncthreads();
            stage_chunk(xb, ch, lds, t);
            __syncthreads();
        }
        const unsigned short* wch = wtpm + (size_t)(ch * KSC) * 2 * 64 * 8;
#pragma unroll
        for (int s = 0; s < KSC; s++) {
            const float* cell = lds + cofs[s];
            float w00 = wg[s][0], w01 = wg[s][1], w10 = wg[s][2], w11 = wg[s][3];
            unsigned pk[4];
#pragma unroll
            for (int jj = 0; jj < 4; jj++) {
                const float* p0 = cell + (2 * jj) * PLS;
                const float* p1 = cell + (2 * jj + 1) * PLS;
                float s0 = p0[0] * w00 + p0[1] * w01 + p0[RS] * w10 + p0[RS + 1] * w11;
                float s1 = p1[0] * w00 + p1[1] * w01 + p1[RS] * w10 + p1[RS + 1] * w11;
                pk[jj] = pack2(s0, s1);
            }
            union { unsigned u[4]; bf16x8 v; } bu;
            bu.u[0] = pk[0]; bu.u[1] = pk[1]; bu.u[2] = pk[2]; bu.u[3] = pk[3];
            const bf16x8* ap = (const bf16x8*)(wch + (size_t)(s * 2) * 64 * 8 + lane * 8);
            acc0 = __builtin_amdgcn_mfma_f32_16x16x32_bf16(ap[0],  bu.v, acc0, 0, 0, 0);
            acc1 = __builtin_amdgcn_mfma_f32_16x16x32_bf16(ap[64], bu.v, acc1, 0, 0, 0);
        }
    }

    // epilogue: BN + ReLU, coalesced stores (col = px)
    const float* SC = bn;
    const float* SH = bn + 32;
    float* op = out + (size_t)b * COUT * 1024 + px;
#pragma unroll
    for (int mt = 0; mt < 2; mt++) {
        f32x4 a = mt ? acc1 : acc0;
#pragma unroll
        for (int reg = 0; reg < 4; reg++) {
            int o = mt * 16 + quad * 4 + reg;
            float v = a[reg] * SC[o] + SH[o];
            op[o * 1024] = fmaxf(v, 0.f);
        }
    }
}

extern "C" void kernel_launch(void* const* d_in, const int* in_sizes, int n_in,
                              void* d_out, int out_size, void* d_ws, size_t ws_size,
                              hipStream_t stream) {
    const float* x      = (const float*)d_in[0];
    const float* w_off  = (const float*)d_in[1];
    const float* b_off  = (const float*)d_in[2];
    const float* w      = (const float*)d_in[3];
    const float* bias   = (const float*)d_in[4];
    const float* gamma  = (const float*)d_in[5];
    const float* beta   = (const float*)d_in[6];
    const float* rmean  = (const float*)d_in[7];
    const float* rvar   = (const float*)d_in[8];
    float* out = (float*)d_out;

    float* ws = (float*)d_ws;
    unsigned short* wtpm = (unsigned short*)(ws + WTPM_W);
    unsigned short* wtpo = (unsigned short*)(ws + WTPO_W);
    float*          bn   = ws + BN_W;

    k_prep <<<36, 256, 0, stream>>>(w, w_off, bias, gamma, beta, rmean, rvar,
                                    wtpm, wtpo, bn);
    k_fused<<<512, 256, 0, stream>>>(x, b_off, wtpo, wtpm, bn, out);
}

// Round 6
// 123.568 us; speedup vs baseline: 2.8654x; 1.1165x over previous
//
#include <hip/hip_runtime.h>

// Deformable conv (K=3,N=9,PAD=1) + BN(eval) + ReLU.  B=32 C=103 H=W=32 Cout=32.
// Round 6: bf16 channel-paired LDS planes (uint = ch-even|ch-odd bf16), halving
// LDS read traffic and footprint; phase-1 reads ARE the B-frag (no pack VALU);
// A-frags staged per-chunk into LDS (L2 weight traffic /4); aligned b128 staging.

#define CC    103
#define COUT  32
#define NCHUNK 7           // 7*16 = 112 >= 103
#define KSC   5            // k-steps (K=32) per chunk
#define RSU   40           // plane row stride (uint entries)
#define COLOFS 3           // padded col 0 lives at entry 3 -> interior writes 16B-aligned
#define PLSU  1364         // pair-plane stride in uints (34*40=1360, +4: 4*PLSU%32=16)
#define NPAIR 8            // channel pairs per chunk
#define PLANES_U (NPAIR * PLSU)     // 10912 uints
#define WFRAG_U  2560               // 10 tiles * 1024B / 4

typedef __attribute__((ext_vector_type(8))) short bf16x8;
typedef __attribute__((ext_vector_type(4))) float f32x4;

// ws layout (floats): wtpm frags [0,17920), wtpo frags [17920,35840), bn [35840,35904)
#define WTPM_W 0
#define WTPO_W 17920
#define BN_W   35840

__device__ __forceinline__ unsigned short f2bf_rne(float f) {
    unsigned u = __float_as_uint(f);
    unsigned r = u + 0x7fffu + ((u >> 16) & 1u);
    return (unsigned short)(r >> 16);
}
// bf16(s0) low16, bf16(s1) high16 (round half up)
__device__ __forceinline__ unsigned pack2(float s0, float s1) {
    unsigned u0 = __float_as_uint(s0) + 0x8000u;
    unsigned u1 = __float_as_uint(s1) + 0x8000u;
    return (u1 & 0xffff0000u) | (u0 >> 16);
}
__device__ __forceinline__ float blo(unsigned u) { return __uint_as_float(u << 16); }
__device__ __forceinline__ float bhi(unsigned u) { return __uint_as_float(u & 0xffff0000u); }

// ---------- prep: weight fragments (A-layout) + BN constants, thread/element ----------
// A-frag 16x16x32: lane l holds A[m=l&15][k=(l>>4)*8+j]. kl=s*32+(l>>4)*8+j;
// n=kl>>4; c=ch*16+(kl&15).  n>=9 / c>=103 / o>=mrows -> 0.
__global__ void k_prep(const float* __restrict__ w, const float* __restrict__ w_off,
                       const float* __restrict__ bias, const float* __restrict__ gamma,
                       const float* __restrict__ beta, const float* __restrict__ mean,
                       const float* __restrict__ var,
                       unsigned short* __restrict__ wtpm, unsigned short* __restrict__ wtpo,
                       float* __restrict__ bn) {
    int tid = blockIdx.x * 256 + threadIdx.x;
    if (tid < 71680) {
        int half = tid >= 35840 ? 1 : 0;
        int e = tid - half * 35840;
        const float* src = half ? w_off : w;
        unsigned short* dst = half ? wtpo : wtpm;
        int mrows = half ? 18 : 32;
        int j = e & 7, lane = (e >> 3) & 63, tile = e >> 9;
        int mt = tile & 1, chs = tile >> 1;
        int s = chs % 5, ch = chs / 5;
        int o = mt * 16 + (lane & 15);
        int kl = s * 32 + (lane >> 4) * 8 + j;
        int n = kl >> 4, c = ch * 16 + (kl & 15);
        float v = 0.f;
        if (n < 9 && c < CC && o < mrows) v = src[o * (CC * 9) + c * 9 + n];
        dst[e] = f2bf_rne(v);
    }
    if (tid < 32) {
        float inv = gamma[tid] * rsqrtf(var[tid] + 1e-5f);
        bn[tid]      = inv;
        bn[32 + tid] = beta[tid] + (bias[tid] - mean[tid]) * inv;
    }
}

// ---------- fused: offset conv (MFMA) -> geometry -> deformable conv (MFMA) ----------
__global__ void __launch_bounds__(256, 2)
k_fused(const float* __restrict__ x, const float* __restrict__ b_off,
        const unsigned short* __restrict__ wtpo, const unsigned short* __restrict__ wtpm,
        const float* __restrict__ bn, float* __restrict__ out) {
    __shared__ unsigned int ldsu[PLANES_U + WFRAG_U];
    __shared__ float exch[18 * 64];
    unsigned int* ldsw = ldsu + PLANES_U;

    int bid = blockIdx.x;
    int b   = (bid & 7) * 4 + ((bid >> 3) & 3);   // XCD swizzle: bid%8 groups share x
    int pxg = bid >> 5;

    int t = threadIdx.x, lane = t & 63, wv = t >> 6;
    int pxl = wv * 16 + (lane & 15);
    int px  = pxg * 64 + pxl;
    int h = px >> 5, wq = px & 31;
    int hi = (lane >> 5) & 1;
    int quad = lane >> 4;
    int pb = (quad & 1) * 4;                      // pair-base (channels pb*2..pb*2+7)

    const int TAPL[5] = {0, 2, 4, 6, 8};
    const int TAPH[5] = {1, 3, 5, 7, 8};          // s=4 hi: tap 8 dup (n=9 weights zero)

    // zero plane region once (padding ring; interior rewritten per chunk)
    for (int i = t; i < PLANES_U; i += 256) ldsu[i] = 0u;

    const float* xb = x + b * (CC * 1024);
    int sr = t >> 3;                              // staging row 0..31
    int sc = (t & 7) * 4;                         // staging col group

    // ================= phase 1: offset conv =================
    f32x4 acc0 = {0.f, 0.f, 0.f, 0.f};
    f32x4 acc1 = {0.f, 0.f, 0.f, 0.f};
    for (int ch = 0; ch < NCHUNK; ch++) {
        __syncthreads();
        { // stage A-frags for this chunk (wtpo)
            const uint4* wsrc4 = (const uint4*)(wtpo + ch * 5120);
            for (int i = t; i < 640; i += 256) ((uint4*)ldsw)[i] = wsrc4[i];
        }
        { // stage 8 channel-pair planes as bf16 pairs
            const float* srcb = xb + sr * 32 + sc;
            unsigned int* dstb = ldsu + (sr + 1) * RSU + COLOFS + 1 + sc;
#pragma unroll
            for (int i = 0; i < NPAIR; i++) {
                int c = ch * 16 + 2 * i;          // uniform -> scalar branch
                if (c < CC) {
                    float4 a = *(const float4*)(srcb + c * 1024);
                    float4 bb = make_float4(0.f, 0.f, 0.f, 0.f);
                    if (c + 1 < CC) bb = *(const float4*)(srcb + (c + 1) * 1024);
                    uint4 o4;
                    o4.x = pack2(a.x, bb.x); o4.y = pack2(a.y, bb.y);
                    o4.z = pack2(a.z, bb.z); o4.w = pack2(a.w, bb.w);
                    *(uint4*)(dstb + i * PLSU) = o4;
                }                                  // c>=103: stale data, zero weights
            }
        }
        __syncthreads();
#pragma unroll
        for (int s = 0; s < KSC; s++) {
            int tap = hi ? TAPH[s] : TAPL[s];
            int ky = tap / 3, kx = tap % 3;
            const unsigned int* cell = ldsu + pb * PLSU + (h + ky) * RSU + COLOFS + (wq + kx);
            union { unsigned int u[4]; bf16x8 v; } bu;
#pragma unroll
            for (int jj = 0; jj < 4; jj++) bu.u[jj] = cell[jj * PLSU];
            bf16x8 a0 = *(const bf16x8*)(ldsw + s * 512 + lane * 4);
            bf16x8 a1 = *(const bf16x8*)(ldsw + s * 512 + 256 + lane * 4);
            acc0 = __builtin_amdgcn_mfma_f32_16x16x32_bf16(a0, bu.v, acc0, 0, 0, 0);
            acc1 = __builtin_amdgcn_mfma_f32_16x16x32_bf16(a1, bu.v, acc1, 0, 0, 0);
        }
    }

    // ================= exchange + geometry + wtpm chunk-6 frags =================
    __syncthreads();                               // phase-1 readers of ldsw/planes done
    {
        float* ex = exch + pxl;
#pragma unroll
        for (int reg = 0; reg < 4; reg++) ex[(quad * 4 + reg) * 64] = acc0[reg];
        if (quad == 0) { ex[16 * 64] = acc1[0]; ex[17 * 64] = acc1[1]; }
    }
    {
        const uint4* wsrc4 = (const uint4*)(wtpm + 6 * 5120);
        for (int i = t; i < 640; i += 256) ((uint4*)ldsw)[i] = wsrc4[i];
    }
    __syncthreads();

    int   cofs[KSC];
    float wg[KSC][4];
#pragma unroll
    for (int s = 0; s < KSC; s++) {
        int tap = hi ? TAPH[s] : TAPL[s];
        float oy = exch[tap * 64 + pxl] + b_off[tap];
        float ox = exch[(9 + tap) * 64 + pxl] + b_off[9 + tap];
        float py  = (float)(h + tap / 3) + oy;     // padded coords
        float pxx = (float)(wq + tap % 3) + ox;
        py  = fminf(fmaxf(py, 0.f), 33.f);
        pxx = fminf(fmaxf(pxx, 0.f), 33.f);
        int y0 = min((int)py, 32);
        int x0 = min((int)pxx, 32);
        float fy = py - (float)y0;
        float fx = pxx - (float)x0;
        wg[s][0] = (1.f - fy) * (1.f - fx);
        wg[s][1] = (1.f - fy) * fx;
        wg[s][2] = fy * (1.f - fx);
        wg[s][3] = fy * fx;
        cofs[s] = pb * PLSU + y0 * RSU + COLOFS + x0;
    }

    // ================= phase 2: deformable conv =================
    acc0 = (f32x4){0.f, 0.f, 0.f, 0.f};
    acc1 = (f32x4){0.f, 0.f, 0.f, 0.f};
    for (int ch = NCHUNK - 1; ch >= 0; ch--) {
        if (ch != NCHUNK - 1) {
            __syncthreads();
            {
                const uint4* wsrc4 = (const uint4*)(wtpm + ch * 5120);
                for (int i = t; i < 640; i += 256) ((uint4*)ldsw)[i] = wsrc4[i];
            }
            {
                const float* srcb = xb + sr * 32 + sc;
                unsigned int* dstb = ldsu + (sr + 1) * RSU + COLOFS + 1 + sc;
#pragma unroll
                for (int i = 0; i < NPAIR; i++) {
                    int c = ch * 16 + 2 * i;
                    if (c < CC) {
                        float4 a = *(const float4*)(srcb + c * 1024);
                        float4 bb = make_float4(0.f, 0.f, 0.f, 0.f);
                        if (c + 1 < CC) bb = *(const float4*)(srcb + (c + 1) * 1024);
                        uint4 o4;
                        o4.x = pack2(a.x, bb.x); o4.y = pack2(a.y, bb.y);
                        o4.z = pack2(a.z, bb.z); o4.w = pack2(a.w, bb.w);
                        *(uint4*)(dstb + i * PLSU) = o4;
                    }
                }
            }
            __syncthreads();
        }
#pragma unroll
        for (int s = 0; s < KSC; s++) {
            const unsigned int* cell = ldsu + cofs[s];
            float w00 = wg[s][0], w01 = wg[s][1], w10 = wg[s][2], w11 = wg[s][3];
            union { unsigned int u[4]; bf16x8 v; } bu;
#pragma unroll
            for (int jj = 0; jj < 4; jj++) {
                unsigned t0 = cell[jj * PLSU];
                unsigned t1 = cell[jj * PLSU + 1];
                unsigned b0 = cell[jj * PLSU + RSU];
                unsigned b1 = cell[jj * PLSU + RSU + 1];
                float se = blo(t0) * w00;
                se = fmaf(blo(t1), w01, se);
                se = fmaf(blo(b0), w10, se);
                se = fmaf(blo(b1), w11, se);
                float so = bhi(t0) * w00;
                so = fmaf(bhi(t1), w01, so);
                so = fmaf(bhi(b0), w10, so);
                so = fmaf(bhi(b1), w11, so);
                bu.u[jj] = pack2(se, so);
            }
            bf16x8 a0 = *(const bf16x8*)(ldsw + s * 512 + lane * 4);
            bf16x8 a1 = *(const bf16x8*)(ldsw + s * 512 + 256 + lane * 4);
            acc0 = __builtin_amdgcn_mfma_f32_16x16x32_bf16(a0, bu.v, acc0, 0, 0, 0);
            acc1 = __builtin_amdgcn_mfma_f32_16x16x32_bf16(a1, bu.v, acc1, 0, 0, 0);
        }
    }

    // epilogue: BN + ReLU, coalesced stores (col = px)
    const float* SC = bn;
    const float* SH = bn + 32;
    float* op = out + (size_t)b * COUT * 1024 + px;
#pragma unroll
    for (int mt = 0; mt < 2; mt++) {
        f32x4 a = mt ? acc1 : acc0;
#pragma unroll
        for (int reg = 0; reg < 4; reg++) {
            int o = mt * 16 + quad * 4 + reg;
            float v = a[reg] * SC[o] + SH[o];
            op[o * 1024] = fmaxf(v, 0.f);
        }
    }
}

extern "C" void kernel_launch(void* const* d_in, const int* in_sizes, int n_in,
                              void* d_out, int out_size, void* d_ws, size_t ws_size,
                              hipStream_t stream) {
    const float* x      = (const float*)d_in[0];
    const float* w_off  = (const float*)d_in[1];
    const float* b_off  = (const float*)d_in[2];
    const float* w      = (const float*)d_in[3];
    const float* bias   = (const float*)d_in[4];
    const float* gamma  = (const float*)d_in[5];
    const float* beta   = (const float*)d_in[6];
    const float* rmean  = (const float*)d_in[7];
    const float* rvar   = (const float*)d_in[8];
    float* out = (float*)d_out;

    float* ws = (float*)d_ws;
    unsigned short* wtpm = (unsigned short*)(ws + WTPM_W);
    unsigned short* wtpo = (unsigned short*)(ws + WTPO_W);
    float*          bn   = ws + BN_W;

    k_prep <<<280, 256, 0, stream>>>(w, w_off, bias, gamma, beta, rmean, rvar,
                                     wtpm, wtpo, bn);
    k_fused<<<512, 256, 0, stream>>>(x, b_off, wtpo, wtpm, bn, out);
}

// Round 8
// 108.789 us; speedup vs baseline: 3.2547x; 1.1359x over previous
//
#include <hip/hip_runtime.h>

// Deformable conv (K=3,N=9,PAD=1) + BN(eval) + ReLU.  B=32 C=103 H=W=32 Cout=32.
// Round 8 (= round-7 theory, compile-fixed): K-split x2 (8-wave blocks: 2 K-halves
// x 4 px-waves -> 4096 waves, 2x occupancy) + f16 packed-pair planes (v_pk_fma
// bilinear, result IS the B-frag word) + mfma_f32_16x16x32_f16. LDS reduction.

#define CC    103
#define COUT  32
#define KSC   5            // k-steps (K=32) per 16-channel chunk
#define RSU   34           // plane row stride (uints)
#define PLSU  1158         // pair-plane stride (34*34=1156, +2: even for b64 writes)
#define NPAIR 8
#define BUF_U (NPAIR * PLSU)        // 9264 uints per half-buffer

typedef __attribute__((ext_vector_type(8))) _Float16 f16x8;
typedef __attribute__((ext_vector_type(2))) _Float16 h2;
typedef __attribute__((ext_vector_type(2))) __fp16  fp16x2;   // cvt_pkrtz return type
typedef __attribute__((ext_vector_type(4))) float f32x4;

// ws layout (floats): wtpm frags [0,17920), wtpo frags [17920,35840), bn [35840,35904)
#define WTPM_W 0
#define WTPO_W 17920
#define BN_W   35840

// ---------- prep: f16 weight fragments (A-layout) + BN constants ----------
// A-frag 16x16x32: lane l holds A[m=l&15][k=(l>>4)*8+j]. kl=s*32+(l>>4)*8+j;
// tap n=kl>>4; c=ch*16+(kl&15).  n>=9 / c>=103 / o>=mrows -> 0.
__global__ void k_prep(const float* __restrict__ w, const float* __restrict__ w_off,
                       const float* __restrict__ bias, const float* __restrict__ gamma,
                       const float* __restrict__ beta, const float* __restrict__ mean,
                       const float* __restrict__ var,
                       unsigned short* __restrict__ wtpm, unsigned short* __restrict__ wtpo,
                       float* __restrict__ bn) {
    int tid = blockIdx.x * 256 + threadIdx.x;
    if (tid < 71680) {
        int half_ = tid >= 35840 ? 1 : 0;
        int e = tid - half_ * 35840;
        const float* src = half_ ? w_off : w;
        unsigned short* dst = half_ ? wtpo : wtpm;
        int mrows = half_ ? 18 : 32;
        int j = e & 7, lane = (e >> 3) & 63, tile = e >> 9;
        int mt = tile & 1, chs = tile >> 1;
        int s = chs % 5, ch = chs / 5;
        int o = mt * 16 + (lane & 15);
        int kl = s * 32 + (lane >> 4) * 8 + j;
        int n = kl >> 4, c = ch * 16 + (kl & 15);
        float v = 0.f;
        if (n < 9 && c < CC && o < mrows) v = src[o * (CC * 9) + c * 9 + n];
        union { _Float16 h; unsigned short u; } cv;
        cv.h = (_Float16)v;
        dst[e] = cv.u;
    }
    if (tid < 32) {
        float inv = gamma[tid] * rsqrtf(var[tid] + 1e-5f);
        bn[tid]      = inv;
        bn[32 + tid] = beta[tid] + (bias[tid] - mean[tid]) * inv;
    }
}

// ---------- fused kernel ----------
__global__ void __launch_bounds__(512, 4)
k_fused(const float* __restrict__ x, const float* __restrict__ b_off,
        const unsigned short* __restrict__ wtpo, const unsigned short* __restrict__ wtpm,
        const float* __restrict__ bn, float* __restrict__ out) {
    __shared__ unsigned int ldsp[2 * BUF_U];
    __shared__ float exch[18 * 64];

    int bid = blockIdx.x;
    int b   = (bid & 7) * 4 + ((bid >> 3) & 3);   // XCD swizzle
    int pxg = bid >> 5;

    int t = threadIdx.x, lane = t & 63, wv = t >> 6;
    int kh = wv >> 2;                 // K-half: 0 -> chunks {1,3,5}, 1 -> {0,2,4,6}
    int pw = wv & 3;
    int pxl = pw * 16 + (lane & 15);
    int px  = pxg * 64 + pxl;
    int h = px >> 5, wq = px & 31;
    int kg = lane >> 4;               // quad
    int hi = kg >> 1;
    int pb = (kg & 1) * 4;            // pair-plane base (channels 2pb..2pb+7)

    unsigned int* mybuf = ldsp + kh * BUF_U;

    for (int i = t; i < 2 * BUF_U; i += 512) ldsp[i] = 0u;

    const float* xb = x + b * (CC * 1024);
    int tl = t & 255;
    int sr = tl >> 3, sk = (tl & 7) * 4;          // staging row / uint-col group

    // per-lane tap tables (lo-quads taps 0,2,4,6,8; hi-quads 1,3,5,7,8; tap8 dup = zero wt)
    const int KYL[5] = {0,0,1,2,2}, KXL[5] = {0,2,1,0,2};
    const int KYH[5] = {0,1,1,2,2}, KXH[5] = {1,0,2,1,2};
    const int TAPL[5] = {0,2,4,6,8}, TAPH[5] = {1,3,5,7,8};
    int myky[5], mykx[5], mytap[5];
#pragma unroll
    for (int s = 0; s < 5; s++) {
        myky[s] = hi ? KYH[s] : KYL[s];
        mykx[s] = hi ? KXH[s] : KXL[s];
        mytap[s] = hi ? TAPH[s] : TAPL[s];
    }

    // stage one 16-channel chunk into my buffer as f16 channel-pairs
    auto stage = [&](int ch) {
        const float* srcb = xb + sr * 32 + sk;
        unsigned int* dstb = mybuf + (sr + 1) * RSU + 2 + sk;
#pragma unroll
        for (int i = 0; i < NPAIR; i++) {
            int c = ch * 16 + 2 * i;              // uniform
            if (c < CC) {
                float4 a = *(const float4*)(srcb + c * 1024);
                float4 bb = make_float4(0.f, 0.f, 0.f, 0.f);
                if (c + 1 < CC) bb = *(const float4*)(srcb + (c + 1) * 1024);
                union { fp16x2 h; unsigned u; } p0, p1, p2, p3;
                p0.h = __builtin_amdgcn_cvt_pkrtz(a.x, bb.x);
                p1.h = __builtin_amdgcn_cvt_pkrtz(a.y, bb.y);
                p2.h = __builtin_amdgcn_cvt_pkrtz(a.z, bb.z);
                p3.h = __builtin_amdgcn_cvt_pkrtz(a.w, bb.w);
                *(uint2*)(dstb + i * PLSU)     = make_uint2(p0.u, p1.u);
                *(uint2*)(dstb + i * PLSU + 2) = make_uint2(p2.u, p3.u);
            }                                     // c>=103: stale-but-finite, zero weights
        }
    };

    f32x4 acc0 = {0.f, 0.f, 0.f, 0.f};
    f32x4 acc1 = {0.f, 0.f, 0.f, 0.f};

    // ================= phase 1: offset conv =================
#pragma unroll
    for (int it = 0; it < 4; it++) {
        const int ch = kh ? (2 * it) : (it < 3 ? 2 * it + 1 : -1);
        __syncthreads();
        if (ch >= 0) stage(ch);
        __syncthreads();
        if (ch >= 0) {
            const unsigned short* wch = wtpo + ch * 5120;
#pragma unroll
            for (int s = 0; s < KSC; s++) {
                const unsigned int* cell = mybuf + pb * PLSU
                                         + (h + myky[s]) * RSU + 1 + (wq + mykx[s]);
                union { unsigned u[4]; f16x8 v; } bu;
#pragma unroll
                for (int jj = 0; jj < 4; jj++) bu.u[jj] = cell[jj * PLSU];
                f16x8 a0 = *(const f16x8*)(wch + s * 1024 + lane * 8);
                f16x8 a1 = *(const f16x8*)(wch + s * 1024 + 512 + lane * 8);
                acc0 = __builtin_amdgcn_mfma_f32_16x16x32_f16(a0, bu.v, acc0, 0, 0, 0);
                acc1 = __builtin_amdgcn_mfma_f32_16x16x32_f16(a1, bu.v, acc1, 0, 0, 0);
            }
        }
    }

    // ---- reduce offset partials across K-halves (C-layout: row=quad*4+reg, col=pxl)
    __syncthreads();
    if (kh == 0) {
        float* ex = exch + pxl;
#pragma unroll
        for (int reg = 0; reg < 4; reg++) ex[(kg * 4 + reg) * 64] = acc0[reg];
        if (kg == 0) { ex[16 * 64] = acc1[0]; ex[17 * 64] = acc1[1]; }
    }
    __syncthreads();
    if (kh == 1) {
        float* ex = exch + pxl;
#pragma unroll
        for (int reg = 0; reg < 4; reg++) ex[(kg * 4 + reg) * 64] += acc0[reg];
        if (kg == 0) { ex[16 * 64] += acc1[0]; ex[17 * 64] += acc1[1]; }
    }
    __syncthreads();

    // ---- geometry (once; every chunk spans all taps)
    int cofs[KSC];
    h2  W[KSC][4];
#pragma unroll
    for (int s = 0; s < KSC; s++) {
        int tap = mytap[s];
        float oy = exch[tap * 64 + pxl] + b_off[tap];
        float ox = exch[(9 + tap) * 64 + pxl] + b_off[9 + tap];
        float py  = (float)(h + myky[s]) + oy;    // padded coords
        float pxx = (float)(wq + mykx[s]) + ox;
        py  = fminf(fmaxf(py, 0.f), 33.f);
        pxx = fminf(fmaxf(pxx, 0.f), 33.f);
        int y0 = min((int)py, 32);
        int x0 = min((int)pxx, 32);
        float fy = py - (float)y0;
        float fx = pxx - (float)x0;
        float w00 = (1.f - fy) * (1.f - fx), w01 = (1.f - fy) * fx;
        float w10 = fy * (1.f - fx),          w11 = fy * fx;
        W[s][0] = (h2){(_Float16)w00, (_Float16)w00};
        W[s][1] = (h2){(_Float16)w01, (_Float16)w01};
        W[s][2] = (h2){(_Float16)w10, (_Float16)w10};
        W[s][3] = (h2){(_Float16)w11, (_Float16)w11};
        cofs[s] = pb * PLSU + y0 * RSU + 1 + x0;
    }

    // ================= phase 2: deformable conv =================
    acc0 = (f32x4){0.f, 0.f, 0.f, 0.f};
    acc1 = (f32x4){0.f, 0.f, 0.f, 0.f};
#pragma unroll
    for (int it = 0; it < 4; it++) {
        // reversed order: it=0 chunk is still resident from phase 1
        const int ch = kh ? (6 - 2 * it) : (it < 3 ? 5 - 2 * it : -1);
        if (it > 0) {
            __syncthreads();
            if (ch >= 0) stage(ch);
            else {  // kh==0, it==3: publish main-conv partials into dead buf0 region
                float* ex2 = (float*)ldsp;
                float* e = ex2 + pxl;
#pragma unroll
                for (int reg = 0; reg < 4; reg++) {
                    e[(kg * 4 + reg) * 64]        = acc0[reg];
                    e[(16 + kg * 4 + reg) * 64]   = acc1[reg];
                }
            }
            __syncthreads();
        }
        if (ch >= 0) {
            const unsigned short* wch = wtpm + ch * 5120;
#pragma unroll
            for (int s = 0; s < KSC; s++) {
                const unsigned int* cell = mybuf + cofs[s];
                union { unsigned u[4]; f16x8 v; } bu;
#pragma unroll
                for (int jj = 0; jj < 4; jj++) {
                    union { unsigned u; h2 hh; } t0, t1, b0, b1;
                    t0.u = cell[jj * PLSU];
                    t1.u = cell[jj * PLSU + 1];
                    b0.u = cell[jj * PLSU + RSU];
                    b1.u = cell[jj * PLSU + RSU + 1];
                    h2 sm = t0.hh * W[s][0] + t1.hh * W[s][1]
                          + b0.hh * W[s][2] + b1.hh * W[s][3];
                    union { h2 hh; unsigned u; } r; r.hh = sm;
                    bu.u[jj] = r.u;
                }
                f16x8 a0 = *(const f16x8*)(wch + s * 1024 + lane * 8);
                f16x8 a1 = *(const f16x8*)(wch + s * 1024 + 512 + lane * 8);
                acc0 = __builtin_amdgcn_mfma_f32_16x16x32_f16(a0, bu.v, acc0, 0, 0, 0);
                acc1 = __builtin_amdgcn_mfma_f32_16x16x32_f16(a1, bu.v, acc1, 0, 0, 0);
            }
        }
    }

    // ---- final reduce + BN + ReLU + store (kh==1 waves; kh==0 published via ex2)
    __syncthreads();
    if (kh == 1) {
        const float* ex2 = (const float*)ldsp;
        float* op = out + (size_t)b * COUT * 1024 + px;
#pragma unroll
        for (int mt = 0; mt < 2; mt++) {
            f32x4 a = mt ? acc1 : acc0;
#pragma unroll
            for (int reg = 0; reg < 4; reg++) {
                int o = mt * 16 + kg * 4 + reg;
                float tot = a[reg] + ex2[o * 64 + pxl];
                float v = tot * bn[o] + bn[32 + o];
                op[o * 1024] = fmaxf(v, 0.f);
            }
        }
    }
}

extern "C" void kernel_launch(void* const* d_in, const int* in_sizes, int n_in,
                              void* d_out, int out_size, void* d_ws, size_t ws_size,
                              hipStream_t stream) {
    const float* x      = (const float*)d_in[0];
    const float* w_off  = (const float*)d_in[1];
    const float* b_off  = (const float*)d_in[2];
    const float* w      = (const float*)d_in[3];
    const float* bias   = (const float*)d_in[4];
    const float* gamma  = (const float*)d_in[5];
    const float* beta   = (const float*)d_in[6];
    const float* rmean  = (const float*)d_in[7];
    const float* rvar   = (const float*)d_in[8];
    float* out = (float*)d_out;

    float* ws = (float*)d_ws;
    unsigned short* wtpm = (unsigned short*)(ws + WTPM_W);
    unsigned short* wtpo = (unsigned short*)(ws + WTPO_W);
    float*          bn   = ws + BN_W;

    k_prep <<<280, 256, 0, stream>>>(w, w_off, bias, gamma, beta, rmean, rvar,
                                     wtpm, wtpo, bn);
    k_fused<<<512, 512, 0, stream>>>(x, b_off, wtpo, wtpm, bn, out);
}

// Round 10
// 108.204 us; speedup vs baseline: 3.2723x; 1.0054x over previous
//
#include <hip/hip_runtime.h>

// Deformable conv (K=3,N=9,PAD=1) + BN(eval) + ReLU.  B=32 C=103 H=W=32 Cout=32.
// Round 10: round-8 known-good dataflow (chunk-split K across two 4-wave halves,
// private per-half buffers, 2 barriers/chunk) + PLSU=1164 (quad bank-offset 16,
// zeroed slack) + register-prefetch staging (global loads for chunk i+1 issued
// before compute of chunk i). f16 pair-planes + mfma_f32_16x16x32_f16.

#define CC    103
#define COUT  32
#define KSC   5            // k-steps (K=32) per 16-channel chunk
#define RSU   34           // plane row stride (uints)
#define PLSU  1164         // 34*34=1156 +8 slack; %8=4 -> pb-quad bank offset 16
#define NPAIR 8
#define BUF_U (NPAIR * PLSU)        // 9312 uints = 37248 B per half-buffer

typedef __attribute__((ext_vector_type(8))) _Float16 f16x8;
typedef __attribute__((ext_vector_type(2))) _Float16 h2;
typedef __attribute__((ext_vector_type(2))) __fp16  fp16x2;   // cvt_pkrtz return type
typedef __attribute__((ext_vector_type(4))) float f32x4;

// ws layout (floats): wtpm frags [0,17920), wtpo frags [17920,35840), bn [35840,35904)
#define WTPM_W 0
#define WTPO_W 17920
#define BN_W   35840

// ---------- prep: f16 weight fragments (A-layout) + BN constants ----------
// A-frag 16x16x32: lane l holds A[m=l&15][k=(l>>4)*8+j]. kl=s*32+(l>>4)*8+j;
// tap n=kl>>4; c=ch*16+(kl&15).  n>=9 / c>=103 / o>=mrows -> 0.
__global__ void k_prep(const float* __restrict__ w, const float* __restrict__ w_off,
                       const float* __restrict__ bias, const float* __restrict__ gamma,
                       const float* __restrict__ beta, const float* __restrict__ mean,
                       const float* __restrict__ var,
                       unsigned short* __restrict__ wtpm, unsigned short* __restrict__ wtpo,
                       float* __restrict__ bn) {
    int tid = blockIdx.x * 256 + threadIdx.x;
    if (tid < 71680) {
        int half_ = tid >= 35840 ? 1 : 0;
        int e = tid - half_ * 35840;
        const float* src = half_ ? w_off : w;
        unsigned short* dst = half_ ? wtpo : wtpm;
        int mrows = half_ ? 18 : 32;
        int j = e & 7, lane = (e >> 3) & 63, tile = e >> 9;
        int mt = tile & 1, chs = tile >> 1;
        int s = chs % 5, ch = chs / 5;
        int o = mt * 16 + (lane & 15);
        int kl = s * 32 + (lane >> 4) * 8 + j;
        int n = kl >> 4, c = ch * 16 + (kl & 15);
        float v = 0.f;
        if (n < 9 && c < CC && o < mrows) v = src[o * (CC * 9) + c * 9 + n];
        union { _Float16 h; unsigned short u; } cv;
        cv.h = (_Float16)v;
        dst[e] = cv.u;
    }
    if (tid < 32) {
        float inv = gamma[tid] * rsqrtf(var[tid] + 1e-5f);
        bn[tid]      = inv;
        bn[32 + tid] = beta[tid] + (bias[tid] - mean[tid]) * inv;
    }
}

// ---------- fused kernel ----------
__global__ void __launch_bounds__(512, 4)
k_fused(const float* __restrict__ x, const float* __restrict__ b_off,
        const unsigned short* __restrict__ wtpo, const unsigned short* __restrict__ wtpm,
        const float* __restrict__ bn, float* __restrict__ out) {
    __shared__ unsigned int ldsp[2 * BUF_U];
    __shared__ float exch[18 * 64];

    int bid = blockIdx.x;
    int b   = (bid & 7) * 4 + ((bid >> 3) & 3);   // XCD swizzle
    int pxg = bid >> 5;

    int t = threadIdx.x, lane = t & 63, wv = t >> 6;
    int kh = wv >> 2;                 // chunk-half: 0 -> chunks {1,3,5}, 1 -> {0,2,4,6}
    int pxl = (wv & 3) * 16 + (lane & 15);
    int px  = pxg * 64 + pxl;
    int h = px >> 5, wq = px & 31;
    int kg = lane >> 4;               // quad
    int hi = kg >> 1;
    int pb = (kg & 1) * 4;            // pair-plane base

    unsigned int* mybuf = ldsp + kh * BUF_U;

    const float* xb = x + b * (CC * 1024);
    int tl = t & 255;
    int sr = tl >> 3, sk = (tl & 7) * 4;          // staging row / col group

    // per-lane tap tables (lo-quads taps 0,2,4,6,8; hi-quads 1,3,5,7,8; tap8 dup = zero wt)
    const int KYL[5] = {0,0,1,2,2}, KXL[5] = {0,2,1,0,2};
    const int KYH[5] = {0,1,1,2,2}, KXH[5] = {1,0,2,1,2};
    const int TAPL[5] = {0,2,4,6,8}, TAPH[5] = {1,3,5,7,8};
    int myky[5], mykx[5], mytap[5];
#pragma unroll
    for (int s = 0; s < 5; s++) {
        myky[s] = hi ? KYH[s] : KYL[s];
        mykx[s] = hi ? KXH[s] : KXL[s];
        mytap[s] = hi ? TAPH[s] : TAPL[s];
    }

    // register-prefetch staging: 16 float4 live across compute (~64 VGPR)
    float4 L[NPAIR], M[NPAIR];
    auto loadx = [&](int ch) {
        const float* s0 = xb + sr * 32 + sk;
#pragma unroll
        for (int i = 0; i < NPAIR; i++) {
            int c = ch * 16 + 2 * i;              // uniform per i
            if (c < CC) {
                L[i] = *(const float4*)(s0 + c * 1024);
                if (c + 1 < CC) M[i] = *(const float4*)(s0 + (c + 1) * 1024);
                else            M[i] = make_float4(0.f, 0.f, 0.f, 0.f);
            }
        }
    };
    auto packwrite = [&](int ch) {
        unsigned int* dstb = mybuf + (sr + 1) * RSU + 2 + sk;
#pragma unroll
        for (int i = 0; i < NPAIR; i++) {
            int c = ch * 16 + 2 * i;
            if (c < CC) {
                union { fp16x2 hh; unsigned u; } p0, p1, p2, p3;
                p0.hh = __builtin_amdgcn_cvt_pkrtz(L[i].x, M[i].x);
                p1.hh = __builtin_amdgcn_cvt_pkrtz(L[i].y, M[i].y);
                p2.hh = __builtin_amdgcn_cvt_pkrtz(L[i].z, M[i].z);
                p3.hh = __builtin_amdgcn_cvt_pkrtz(L[i].w, M[i].w);
                *(uint2*)(dstb + i * PLSU)     = make_uint2(p0.u, p1.u);
                *(uint2*)(dstb + i * PLSU + 2) = make_uint2(p2.u, p3.u);
            }                                     // c>=103: stale-but-finite, zero weights
        }
    };

    auto chunk1 = [&](int it) { return kh ? (2 * it) : (it < 3 ? 2 * it + 1 : -1); };
    auto chunk2 = [&](int it) { return kh ? (6 - 2 * it) : (it < 3 ? 5 - 2 * it : -1); };

    f32x4 acc0 = {0.f, 0.f, 0.f, 0.f};
    f32x4 acc1 = {0.f, 0.f, 0.f, 0.f};

    // prologue: prefetch first chunk, zero buffers (pad ring + slack)
    loadx(chunk1(0));
    for (int i = t; i < 2 * BUF_U; i += 512) ldsp[i] = 0u;
    __syncthreads();

    // ================= phase 1: offset conv =================
    for (int it = 0; it < 4; it++) {
        int ch = chunk1(it);
        if (ch >= 0) packwrite(ch);
        __syncthreads();                          // staging visible
        int nx = (it < 3) ? chunk1(it + 1) : -1;
        if (nx >= 0) loadx(nx);                   // globals hide under compute
        if (ch >= 0) {
            const unsigned short* wch = wtpo + ch * 5120;
#pragma unroll
            for (int s = 0; s < KSC; s++) {
                const unsigned int* cell = mybuf + pb * PLSU
                    + (h + myky[s]) * RSU + 1 + (wq + mykx[s]);
                union { unsigned u[4]; f16x8 v; } bu;
#pragma unroll
                for (int jj = 0; jj < 4; jj++) bu.u[jj] = cell[jj * PLSU];
                f16x8 a0 = *(const f16x8*)(wch + s * 1024 + lane * 8);
                f16x8 a1 = *(const f16x8*)(wch + s * 1024 + 512 + lane * 8);
                acc0 = __builtin_amdgcn_mfma_f32_16x16x32_f16(a0, bu.v, acc0, 0, 0, 0);
                acc1 = __builtin_amdgcn_mfma_f32_16x16x32_f16(a1, bu.v, acc1, 0, 0, 0);
            }
        }
        __syncthreads();                          // compute done before next overwrite
    }

    // ---- reduce offset partials across halves (C-layout: row=kg*4+reg, col=pxl)
    if (kh == 0) {
        float* ex = exch + pxl;
#pragma unroll
        for (int reg = 0; reg < 4; reg++) ex[(kg * 4 + reg) * 64] = acc0[reg];
        if (kg == 0) { ex[16 * 64] = acc1[0]; ex[17 * 64] = acc1[1]; }
    }
    __syncthreads();
    if (kh == 1) {
        float* ex = exch + pxl;
#pragma unroll
        for (int reg = 0; reg < 4; reg++) ex[(kg * 4 + reg) * 64] += acc0[reg];
        if (kg == 0) { ex[16 * 64] += acc1[0]; ex[17 * 64] += acc1[1]; }
    }
    __syncthreads();

    // ---- geometry (once; 5 slots per lane)
    int cofs[KSC];
    h2  W[KSC][4];
#pragma unroll
    for (int s = 0; s < KSC; s++) {
        int tap = mytap[s];
        float oy = exch[tap * 64 + pxl] + b_off[tap];
        float ox = exch[(9 + tap) * 64 + pxl] + b_off[9 + tap];
        float py  = (float)(h + myky[s]) + oy;    // padded coords
        float pxx = (float)(wq + mykx[s]) + ox;
        py  = fminf(fmaxf(py, 0.f), 33.f);
        pxx = fminf(fmaxf(pxx, 0.f), 33.f);
        int y0 = min((int)py, 32);
        int x0 = min((int)pxx, 32);
        float fy = py - (float)y0;
        float fx = pxx - (float)x0;
        float w00 = (1.f - fy) * (1.f - fx), w01 = (1.f - fy) * fx;
        float w10 = fy * (1.f - fx),          w11 = fy * fx;
        W[s][0] = (h2){(_Float16)w00, (_Float16)w00};
        W[s][1] = (h2){(_Float16)w01, (_Float16)w01};
        W[s][2] = (h2){(_Float16)w10, (_Float16)w10};
        W[s][3] = (h2){(_Float16)w11, (_Float16)w11};
        cofs[s] = pb * PLSU + y0 * RSU + 1 + x0;
    }

    // ================= phase 2: deformable conv (chunks reversed; first resident) ====
    acc0 = (f32x4){0.f, 0.f, 0.f, 0.f};
    acc1 = (f32x4){0.f, 0.f, 0.f, 0.f};
    for (int it = 0; it < 4; it++) {
        int ch = chunk2(it);
        if (it > 0) {
            if (ch >= 0) packwrite(ch);
            else {  // kh==0, it==3: publish main partials into kh0's dead buffer
                float* e = (float*)ldsp + pxl;
#pragma unroll
                for (int reg = 0; reg < 4; reg++) {
                    e[(kg * 4 + reg) * 64]      = acc0[reg];
                    e[(16 + kg * 4 + reg) * 64] = acc1[reg];
                }
            }
        }
        __syncthreads();
        int nx = (it < 3) ? chunk2(it + 1) : -1;
        if (nx >= 0) loadx(nx);
        if (ch >= 0) {
            const unsigned short* wch = wtpm + ch * 5120;
#pragma unroll
            for (int s = 0; s < KSC; s++) {
                const unsigned int* cell = mybuf + cofs[s];
                union { unsigned u[4]; f16x8 v; } bu;
#pragma unroll
                for (int jj = 0; jj < 4; jj++) {
                    union { unsigned u; h2 hh; } t0, t1, b0, b1;
                    t0.u = cell[jj * PLSU];
                    t1.u = cell[jj * PLSU + 1];
                    b0.u = cell[jj * PLSU + RSU];
                    b1.u = cell[jj * PLSU + RSU + 1];
                    h2 sm = t0.hh * W[s][0] + t1.hh * W[s][1]
                          + b0.hh * W[s][2] + b1.hh * W[s][3];
                    union { h2 hh; unsigned u; } r; r.hh = sm;
                    bu.u[jj] = r.u;
                }
                f16x8 a0 = *(const f16x8*)(wch + s * 1024 + lane * 8);
                f16x8 a1 = *(const f16x8*)(wch + s * 1024 + 512 + lane * 8);
                acc0 = __builtin_amdgcn_mfma_f32_16x16x32_f16(a0, bu.v, acc0, 0, 0, 0);
                acc1 = __builtin_amdgcn_mfma_f32_16x16x32_f16(a1, bu.v, acc1, 0, 0, 0);
            }
        }
        __syncthreads();
    }

    // ---- final reduce + BN + ReLU + store (kh1 adds kh0's published partials)
    if (kh == 1) {
        const float* ex2 = (const float*)ldsp;
        float* op = out + (size_t)b * COUT * 1024 + px;
#pragma unroll
        for (int mt = 0; mt < 2; mt++) {
            f32x4 a = mt ? acc1 : acc0;
#pragma unroll
            for (int reg = 0; reg < 4; reg++) {
                int o = mt * 16 + kg * 4 + reg;
                float tot = a[reg] + ex2[o * 64 + pxl];
                float v = tot * bn[o] + bn[32 + o];
                op[o * 1024] = fmaxf(v, 0.f);
            }
        }
    }
}

extern "C" void kernel_launch(void* const* d_in, const int* in_sizes, int n_in,
                              void* d_out, int out_size, void* d_ws, size_t ws_size,
                              hipStream_t stream) {
    const float* x      = (const float*)d_in[0];
    const float* w_off  = (const float*)d_in[1];
    const float* b_off  = (const float*)d_in[2];
    const float* w      = (const float*)d_in[3];
    const float* bias   = (const float*)d_in[4];
    const float* gamma  = (const float*)d_in[5];
    const float* beta   = (const float*)d_in[6];
    const float* rmean  = (const float*)d_in[7];
    const float* rvar   = (const float*)d_in[8];
    float* out = (float*)d_out;

    float* ws = (float*)d_ws;
    unsigned short* wtpm = (unsigned short*)(ws + WTPM_W);
    unsigned short* wtpo = (unsigned short*)(ws + WTPO_W);
    float*          bn   = ws + BN_W;

    k_prep <<<280, 256, 0, stream>>>(w, w_off, bias, gamma, beta, rmean, rvar,
                                     wtpm, wtpo, bn);
    k_fused<<<512, 512, 0, stream>>>(x, b_off, wtpo, wtpm, bn, out);
}